// Round 11
// baseline (475.977 us; speedup 1.0000x reference)
//
#include <hip/hip_runtime.h>
#include <math.h>

#define BB 16
#define TT 512
#define IND 128
#define HH 256
#define DD 8
#define EPSF 1e-5f

typedef _Float16 h2_t __attribute__((ext_vector_type(2)));
typedef float f32x4 __attribute__((ext_vector_type(4)));

__device__ __forceinline__ float fast_tanh(float x) {
    // exp->inf gives 1, exp->0 gives -1; no clamp needed (verified r4-r10, same absmax)
    const float e = __expf(2.f * x);
    return 1.f - __fdividef(2.f, e + 1.f);
}

// quad_perm XOR swaps on the VALU pipe (no LDS traffic)
__device__ __forceinline__ float dpp_xor1(float x) {
    int i = __builtin_bit_cast(int, x);
    i = __builtin_amdgcn_update_dpp(i, i, 0xB1, 0xF, 0xF, true);  // {1,0,3,2}
    return __builtin_bit_cast(float, i);
}
__device__ __forceinline__ float dpp_xor2(float x) {
    int i = __builtin_bit_cast(int, x);
    i = __builtin_amdgcn_update_dpp(i, i, 0x4E, 0xF, 0xF, true);  // {2,3,0,1}
    return __builtin_bit_cast(float, i);
}

// ---------------- K1: x_proj[b,t,j] = y[b,t,:]·W_ih[j,:] + b_ih[j] + b_hh[j] ----------------
__global__ __launch_bounds__(512, 4) void xproj_kernel(
    const float* __restrict__ y, const float* __restrict__ W_ih,
    const float* __restrict__ b_ih, const float* __restrict__ b_hh,
    float* __restrict__ xp)
{
    __shared__ __align__(16) float ylds[16 * IND];  // 8 KB
    const int tid = threadIdx.x;
    const int j = tid >> 1;
    const int k4 = (tid & 1) * 4;

    float4 w[16];
    const float* wr = W_ih + (size_t)j * IND + k4;
#pragma unroll
    for (int i = 0; i < 16; ++i) w[i] = *(const float4*)(wr + i * 8);
#pragma unroll
    for (int i = 0; i < 16; ++i)
        asm volatile("" : "+v"(w[i].x), "+v"(w[i].y), "+v"(w[i].z), "+v"(w[i].w));
    const float bias = b_ih[j] + b_hh[j];

    const int row0 = blockIdx.x * 16;
    ((float4*)ylds)[tid] = ((const float4*)(y + (size_t)row0 * IND))[tid];
    __syncthreads();

#pragma unroll 4
    for (int r = 0; r < 16; ++r) {
        const float* yr = ylds + r * IND + k4;
        float a0 = 0.f, a1 = 0.f, a2 = 0.f, a3 = 0.f;
#pragma unroll
        for (int i = 0; i < 16; ++i) {
            const float4 hv = *(const float4*)(yr + i * 8);
            a0 = fmaf(hv.x, w[i].x, a0);
            a1 = fmaf(hv.y, w[i].y, a1);
            a2 = fmaf(hv.z, w[i].z, a2);
            a3 = fmaf(hv.w, w[i].w, a3);
        }
        float acc = (a0 + a1) + (a2 + a3);
        acc += dpp_xor1(acc);
        if ((tid & 1) == 0) xp[(size_t)(row0 + r) * HH + j] = acc + bias;
    }
}

// ---------------- K2: fused RNN scan + heads + tridiag (blocks 0..15), fill (blocks 16..) ----
// Scan: r1/r7-proven structure (256 thr, lane (j0,k) owns cols {j0+64m} over a 64-elem
// slice, 128 fdot2, DPP quad reduce, lgkm-only barrier, 4-deep xp prefetch).
// LDS-FREE fused heads: head row g (24 = 8 mean + 8 diag + 8 off) is mapped to quad
// j0==g; its 4 lanes REUSE the u8 registers (the h-slice already loaded for the
// recurrence) -> zero extra LDS traffic. +32 fdot2 on quads 0..23 only (waves 2,3 skip
// via execz); reduce = same 2-DPP butterfly; lane k==0 writes: g<8 -> mean row t-1
// directly, 8<=g<24 -> svw[g-8] (diag/off). Two steps later lanes tid<8 emit prec row
// r=t-2: (r,r)=diag^2+offp^2+eps, (r,r+1)=(r+1,r)=diag*off, running ptr += 513.
// Rows 510/511 via epilogue. Fill blocks zero prec but SKIP |c-r|<=1 cells exactly
// (scan-written; disjoint -> no race). enc workspace/K3 eliminated.
__global__ __launch_bounds__(256, 1) void scan_fill_kernel(
    const float* __restrict__ xp, const float* __restrict__ W_hh,
    const float* __restrict__ W_mean, const float* __restrict__ b_mean,
    const float* __restrict__ W_bd, const float* __restrict__ b_bd,
    float* __restrict__ mean_out, float* __restrict__ prec)
{
    if (blockIdx.x >= BB) {
        // zero-fill prec, skipping tridiagonal cells (written by scan blocks)
        const size_t nchunks = (size_t)BB * DD * TT * TT / 4;
        const f32x4 z = {0.f, 0.f, 0.f, 0.f};
        size_t idx = (size_t)(blockIdx.x - BB) * blockDim.x + threadIdx.x;
        const size_t stride = (size_t)(gridDim.x - BB) * blockDim.x;
        for (; idx < nchunks; idx += stride) {
            const int rem = (int)(idx & 65535);   // 65536 chunks per 512x512 matrix
            const int r  = rem >> 7;              // 128 chunks per row
            const int c0 = (rem & 127) << 2;
            float* p = prec + idx * 4;
            if (c0 + 3 < r - 1 || c0 > r + 1) {
                *(f32x4*)p = z;
            } else {
#pragma unroll
                for (int e = 0; e < 4; ++e) {
                    const int c = c0 + e;
                    if (c < r - 1 || c > r + 1) p[e] = 0.f;
                }
            }
        }
        return;
    }

    const int b   = blockIdx.x;
    const int tid = threadIdx.x;
    const int j0  = tid >> 2;      // 0..63 (quad id)
    const int k   = tid & 3;       // 64-elem slice AND owned-col selector
    const int jw  = j0 + 64 * k;   // col this lane finalizes

    // h layout: slice s at byte s*144, col j at (j>>6)*144 + (j&63)*2
    __shared__ __align__(16) char hbufA[4 * 144];
    __shared__ __align__(16) char hbufB[4 * 144];
    __shared__ float svA[16], svB[16];   // diag/off S-values, double-buffered

    // recurrence weights: w[m][i] = W_hh[j0+64m][64k+2i..+1] (64 VGPR)
    h2_t w[4][32];
#pragma unroll
    for (int m = 0; m < 4; ++m) {
        const float* wr = W_hh + (size_t)(j0 + 64 * m) * HH + (size_t)k * 64;
#pragma unroll
        for (int i = 0; i < 32; ++i) {
            h2_t v;
            v.x = (_Float16)wr[2 * i];
            v.y = (_Float16)wr[2 * i + 1];
            w[m][i] = v;
        }
    }
#pragma unroll
    for (int m = 0; m < 4; ++m)
#pragma unroll
        for (int i = 0; i < 32; ++i) {
            int tmp = __builtin_bit_cast(int, w[m][i]);
            asm volatile("" : "+v"(tmp));
            w[m][i] = __builtin_bit_cast(h2_t, tmp);
        }

    // head row g = j0 (quads 0..23 active); slice = this lane's existing 64-elem slice
    const bool hv = (j0 < 24);
    const float hbias = hv ? ((j0 < 8) ? b_mean[j0] : b_bd[j0 - 8]) : 0.f;

    // head weights: 64 floats of row g, slice k -> 32 h2 (32 VGPR), pinned
    h2_t wh[32];
    {
        const float* hrow = hv ? ((j0 < 8) ? W_mean + (size_t)j0 * HH
                                           : W_bd + (size_t)(j0 - 8) * HH)
                               : W_mean;
        const float* hp0 = hrow + 64 * k;
#pragma unroll
        for (int i = 0; i < 32; ++i) {
            h2_t v;
            v.x = (_Float16)hp0[2 * i];
            v.y = (_Float16)hp0[2 * i + 1];
            wh[i] = v;
        }
    }
#pragma unroll
    for (int i = 0; i < 32; ++i) {
        int tmp = __builtin_bit_cast(int, wh[i]);
        asm volatile("" : "+v"(tmp));
        wh[i] = __builtin_bit_cast(h2_t, tmp);
    }

    // zero-init hbufA
    if (tid < 128) {
        const int m = 2 * tid;
        h2_t z; z.x = (_Float16)0.f; z.y = (_Float16)0.f;
        *(h2_t*)(hbufA + (m >> 6) * 144 + (m & 63) * 2) = z;
    }

    const float* xpb = xp + (size_t)b * TT * HH;
    float xbuf[4];
#pragma unroll
    for (int s = 0; s < 4; ++s) xbuf[s] = xpb[(size_t)s * HH + jw];
    const float* xpf = xpb + (size_t)4 * HH + jw;

    const int roff = k * 144;            // slice base (read)
    const int hoff = k * 144 + j0 * 2;   // h write addr for col jw

    // output pointers
    float* mpp = mean_out + (size_t)b * TT * DD + j0 - DD;       // col j0, row -1 (+8/step)
    float* pr  = prec + ((size_t)b * DD + (tid & 7)) * TT * TT;  // row 0 diag (+=513)
    float offp = 0.f;

    __syncthreads();

    const char* hrd = hbufA;
    char* hwr = hbufB;
    float* svr = svA;   // holds S-row t-2 during step t
    float* svw = svB;

#define SCAN_STEP(S, PF, MW, PA)                                                  \
    {                                                                             \
        const float xc = xbuf[S];                                                 \
        if (PF) xbuf[S] = xpf[(S) * HH];                                          \
        const float4* hp = (const float4*)(hrd + roff);                           \
        float4 u8[8];                                                             \
        _Pragma("unroll")                                                         \
        for (int i = 0; i < 8; ++i) u8[i] = hp[i];                                \
        if (PA) {                                                                 \
            if (tid < 8) {                                                        \
                const float dg = svr[tid];                                        \
                const float of = svr[8 + tid];                                    \
                pr[0] = dg * dg + offp * offp + EPSF;                             \
                const float s2 = dg * of;                                         \
                pr[1] = s2;                                                       \
                pr[TT] = s2;                                                      \
                offp = of;                                                        \
                pr += TT + 1;                                                     \
            }                                                                     \
        }                                                                         \
        float a0 = 0.f, a1 = 0.f, a2 = 0.f, a3 = 0.f;                             \
        _Pragma("unroll")                                                         \
        for (int i = 0; i < 8; ++i) {                                             \
            union { float4 f4; h2_t h[4]; } u;                                    \
            u.f4 = u8[i];                                                         \
            _Pragma("unroll")                                                     \
            for (int q = 0; q < 4; ++q) {                                         \
                a0 = __builtin_amdgcn_fdot2(u.h[q], w[0][4 * i + q], a0, false);  \
                a1 = __builtin_amdgcn_fdot2(u.h[q], w[1][4 * i + q], a1, false);  \
                a2 = __builtin_amdgcn_fdot2(u.h[q], w[2][4 * i + q], a2, false);  \
                a3 = __builtin_amdgcn_fdot2(u.h[q], w[3][4 * i + q], a3, false);  \
            }                                                                     \
        }                                                                         \
        if (hv) {                                                                 \
            float hacc = 0.f;                                                     \
            _Pragma("unroll")                                                     \
            for (int i = 0; i < 8; ++i) {                                         \
                union { float4 f4; h2_t h[4]; } v;                                \
                v.f4 = u8[i];                                                     \
                _Pragma("unroll")                                                 \
                for (int q = 0; q < 4; ++q)                                       \
                    hacc = __builtin_amdgcn_fdot2(v.h[q], wh[4 * i + q], hacc, false); \
            }                                                                     \
            hacc += dpp_xor1(hacc); hacc += dpp_xor2(hacc);                       \
            if (k == 0) {                                                         \
                const float S_ = hacc + hbias;                                    \
                if (j0 < 8) { if (MW) mpp[0] = S_; }                              \
                else svw[j0 - 8] = S_;                                            \
            }                                                                     \
        }                                                                         \
        a0 += dpp_xor1(a0); a0 += dpp_xor2(a0);                                   \
        a1 += dpp_xor1(a1); a1 += dpp_xor2(a1);                                   \
        a2 += dpp_xor1(a2); a2 += dpp_xor2(a2);                                   \
        a3 += dpp_xor1(a3); a3 += dpp_xor2(a3);                                   \
        const float p = (k & 1) ? ((k & 2) ? a3 : a1) : ((k & 2) ? a2 : a0);      \
        const float hn = fast_tanh(xc + p);                                       \
        *(_Float16*)(hwr + hoff) = (_Float16)hn;                                  \
        mpp += DD;                                                                \
        asm volatile("s_waitcnt lgkmcnt(0)\n\ts_barrier" ::: "memory");           \
        { const char* t1 = hrd; hrd = hwr; hwr = (char*)t1; }                     \
        { float* t2 = svr; svr = svw; svw = t2; }                                 \
    }

    // first group peeled: t=0 (no mean row -1, no phase A), t=1 (mean row 0), t=2,3 full
    SCAN_STEP(0, 1, 0, 0)
    SCAN_STEP(1, 1, 1, 0)
    SCAN_STEP(2, 1, 1, 1)
    SCAN_STEP(3, 1, 1, 1)
    xpf += 4 * HH;
    // main groups t=4..507, prefetch t+4..t+7 (max 511)
    for (int tb = 4; tb < TT - 4; tb += 4) {
        SCAN_STEP(0, 1, 1, 1)
        SCAN_STEP(1, 1, 1, 1)
        SCAN_STEP(2, 1, 1, 1)
        SCAN_STEP(3, 1, 1, 1)
        xpf += 4 * HH;
    }
    // tail t=508..511: already prefetched
    SCAN_STEP(0, 0, 1, 1)
    SCAN_STEP(1, 0, 1, 1)
    SCAN_STEP(2, 0, 1, 1)
    SCAN_STEP(3, 0, 1, 1)
#undef SCAN_STEP

    // ---- epilogue 1: prec row 510 (svr), head dots on enc[511] (= hrd), mean row 511 ----
    if (tid < 8) {
        const float dg = svr[tid];
        const float of = svr[8 + tid];
        pr[0] = dg * dg + offp * offp + EPSF;
        const float s2 = dg * of;
        pr[1] = s2;
        pr[TT] = s2;
        offp = of;
        pr += TT + 1;
    }
    if (hv) {
        float hacc = 0.f;
        const float4* hp = (const float4*)(hrd + roff);
#pragma unroll
        for (int i = 0; i < 8; ++i) {
            union { float4 f4; h2_t h[4]; } v;
            v.f4 = hp[i];
#pragma unroll
            for (int q = 0; q < 4; ++q)
                hacc = __builtin_amdgcn_fdot2(v.h[q], wh[4 * i + q], hacc, false);
        }
        hacc += dpp_xor1(hacc); hacc += dpp_xor2(hacc);
        if (k == 0) {
            const float S_ = hacc + hbias;
            if (j0 < 8) mpp[0] = S_;          // mean row 511
            else svw[j0 - 8] = S_;            // S-row 511
        }
    }
    asm volatile("s_waitcnt lgkmcnt(0)\n\ts_barrier" ::: "memory");
    // ---- epilogue 2: prec row 511 (no super/sub-diagonal) ----
    if (tid < 8) {
        const float dg = svw[tid];
        pr[0] = dg * dg + offp * offp + EPSF;
    }
}

extern "C" void kernel_launch(void* const* d_in, const int* in_sizes, int n_in,
                              void* d_out, int out_size, void* d_ws, size_t ws_size,
                              hipStream_t stream) {
    const float* y      = (const float*)d_in[0];
    const float* W_ih   = (const float*)d_in[1];
    const float* W_hh   = (const float*)d_in[2];
    const float* b_ih   = (const float*)d_in[3];
    const float* b_hh   = (const float*)d_in[4];
    const float* W_mean = (const float*)d_in[5];
    const float* b_mean = (const float*)d_in[6];
    const float* W_bd   = (const float*)d_in[7];
    const float* b_bd   = (const float*)d_in[8];

    float* out  = (float*)d_out;
    float* mean = out;                              // B*T*D floats
    float* prec = out + (size_t)BB * TT * DD;       // B*D*T*T floats

    float* xp = (float*)d_ws;                       // B*T*H floats = 8 MB

    xproj_kernel<<<512, 512, 0, stream>>>(y, W_ih, b_ih, b_hh, xp);
    scan_fill_kernel<<<512, 256, 0, stream>>>(xp, W_hh, W_mean, b_mean, W_bd, b_bd,
                                              mean, prec);
}

// Round 12
// 408.505 us; speedup vs baseline: 1.1652x; 1.1652x over previous
//
#include <hip/hip_runtime.h>
#include <math.h>

#define BB 16
#define TT 512
#define IND 128
#define HH 256
#define DD 8
#define EPSF 1e-5f

typedef _Float16 h2_t __attribute__((ext_vector_type(2)));
typedef float f32x4 __attribute__((ext_vector_type(4)));

__device__ __forceinline__ float fast_tanh(float x) {
    // exp->inf gives 1, exp->0 gives -1; no clamp needed (verified r4-r11, same absmax)
    const float e = __expf(2.f * x);
    return 1.f - __fdividef(2.f, e + 1.f);
}

// quad_perm XOR swaps on the VALU pipe (no LDS traffic)
__device__ __forceinline__ float dpp_xor1(float x) {
    int i = __builtin_bit_cast(int, x);
    i = __builtin_amdgcn_update_dpp(i, i, 0xB1, 0xF, 0xF, true);  // {1,0,3,2}
    return __builtin_bit_cast(float, i);
}
__device__ __forceinline__ float dpp_xor2(float x) {
    int i = __builtin_bit_cast(int, x);
    i = __builtin_amdgcn_update_dpp(i, i, 0x4E, 0xF, 0xF, true);  // {2,3,0,1}
    return __builtin_bit_cast(float, i);
}

// ---------------- K1: x_proj[b,t,j] = y[b,t,:]·W_ih[j,:] + b_ih[j] + b_hh[j] ----------------
// All 16 rows staged in ONE coalesced burst + ONE barrier; DPP pair-reduce.
__global__ __launch_bounds__(512, 4) void xproj_kernel(
    const float* __restrict__ y, const float* __restrict__ W_ih,
    const float* __restrict__ b_ih, const float* __restrict__ b_hh,
    float* __restrict__ xp)
{
    __shared__ __align__(16) float ylds[16 * IND];  // 8 KB
    const int tid = threadIdx.x;
    const int j = tid >> 1;
    const int k4 = (tid & 1) * 4;

    float4 w[16];
    const float* wr = W_ih + (size_t)j * IND + k4;
#pragma unroll
    for (int i = 0; i < 16; ++i) w[i] = *(const float4*)(wr + i * 8);
#pragma unroll
    for (int i = 0; i < 16; ++i)
        asm volatile("" : "+v"(w[i].x), "+v"(w[i].y), "+v"(w[i].z), "+v"(w[i].w));
    const float bias = b_ih[j] + b_hh[j];

    const int row0 = blockIdx.x * 16;
    ((float4*)ylds)[tid] = ((const float4*)(y + (size_t)row0 * IND))[tid];
    __syncthreads();

#pragma unroll 4
    for (int r = 0; r < 16; ++r) {
        const float* yr = ylds + r * IND + k4;
        float a0 = 0.f, a1 = 0.f, a2 = 0.f, a3 = 0.f;
#pragma unroll
        for (int i = 0; i < 16; ++i) {
            const float4 hv = *(const float4*)(yr + i * 8);
            a0 = fmaf(hv.x, w[i].x, a0);
            a1 = fmaf(hv.y, w[i].y, a1);
            a2 = fmaf(hv.z, w[i].z, a2);
            a3 = fmaf(hv.w, w[i].w, a3);
        }
        float acc = (a0 + a1) + (a2 + a3);
        acc += dpp_xor1(acc);
        if ((tid & 1) == 0) xp[(size_t)(row0 + r) * HH + j] = acc + bias;
    }
}

// ---------------- K2: RNN scan (blocks 0..15) + prec zero-fill (blocks 16..) ----------------
// r1-proven structure (verified best: scan 252 us): 256 threads (4 waves), lane
// (j0 = tid>>2, k = tid&3) owns cols {j0+64m} with a 64-elem k-slice: 128 fdot2/lane,
// 64 weight VGPRs, 8 ds_read_b128/lane (144-B slice pitch, conflict-free), DPP quad
// reduce, all-lane b16 h-write, lgkm-only barrier (keeps 4-deep xp register prefetch in
// flight). Running pointers bumped once per 4-step group; last 4 steps peeled.
// Structural ledger (r2-r11): MFMA x3, wave-widening, shared-barrier teams, head-fusion
// x2 all regressed -- this is the measured optimum; scan is dot2-issue-bound (per-CU
// VALUBusy ~61%) on a serial chain with 1 wave/SIMD.
__global__ __launch_bounds__(256, 2) void scan_fill_kernel(
    const float* __restrict__ xp, const float* __restrict__ W_hh,
    float* __restrict__ enc, float* __restrict__ prec)
{
    if (blockIdx.x >= BB) {
        const size_t n4 = (size_t)BB * DD * TT * TT / 4;
        const f32x4 z = {0.f, 0.f, 0.f, 0.f};
        f32x4* p4 = (f32x4*)prec;
        size_t idx = (size_t)(blockIdx.x - BB) * blockDim.x + threadIdx.x;
        const size_t stride = (size_t)(gridDim.x - BB) * blockDim.x;
        for (; idx < n4; idx += stride) p4[idx] = z;
        return;
    }

    const int b   = blockIdx.x;
    const int tid = threadIdx.x;
    const int j0  = tid >> 2;      // 0..63
    const int k   = tid & 3;       // 64-elem slice AND owned-col selector
    const int jw  = j0 + 64 * k;   // col this lane finalizes

    // h layout: slice s at byte s*144, col j at (j>>6)*144 + (j&63)*2
    __shared__ __align__(16) char hbufA[4 * 144];
    __shared__ __align__(16) char hbufB[4 * 144];

    // weights: w[m][i] = (W_hh[j0+64m][64k+2i], W_hh[j0+64m][64k+2i+1]), i<32 (64 VGPR)
    h2_t w[4][32];
#pragma unroll
    for (int m = 0; m < 4; ++m) {
        const float* wr = W_hh + (size_t)(j0 + 64 * m) * HH + (size_t)k * 64;
#pragma unroll
        for (int i = 0; i < 32; ++i) {
            h2_t v;
            v.x = (_Float16)wr[2 * i];
            v.y = (_Float16)wr[2 * i + 1];
            w[m][i] = v;
        }
    }
#pragma unroll
    for (int m = 0; m < 4; ++m)
#pragma unroll
        for (int i = 0; i < 32; ++i) {
            int tmp = __builtin_bit_cast(int, w[m][i]);
            asm volatile("" : "+v"(tmp));
            w[m][i] = __builtin_bit_cast(h2_t, tmp);
        }

    // zero-init hbufA (pads don't matter: never read)
    if (tid < 128) {
        const int m = 2 * tid;
        h2_t z; z.x = (_Float16)0.f; z.y = (_Float16)0.f;
        *(h2_t*)(hbufA + (m >> 6) * 144 + (m & 63) * 2) = z;
    }

    const float* xpb  = xp  + (size_t)b * TT * HH;

    // 4-deep rotating xp prefetch; xpf points at the next prefetch group (t=4..7)
    float xbuf[4];
#pragma unroll
    for (int s = 0; s < 4; ++s) xbuf[s] = xpb[(size_t)s * HH + jw];
    const float* xpf = xpb + (size_t)4 * HH + jw;
    float*      encp = enc + (size_t)b * TT * HH + jw;

    const int roff = k * 144;            // LDS read base (slice k)
    const int hoff = k * 144 + j0 * 2;   // LDS write addr for col jw

    __syncthreads();

    const char* hrd = hbufA;
    char* hwr = hbufB;

#define SCAN_STEP(S, PF)                                                          \
    {                                                                             \
        const float xc = xbuf[S];                                                 \
        if (PF) xbuf[S] = xpf[(S) * HH];                                          \
        float a0 = 0.f, a1 = 0.f, a2 = 0.f, a3 = 0.f;                             \
        const float4* hp = (const float4*)(hrd + roff);                           \
        _Pragma("unroll")                                                         \
        for (int i = 0; i < 8; ++i) {                                             \
            union { float4 f4; h2_t h[4]; } u;                                    \
            u.f4 = hp[i];                                                         \
            _Pragma("unroll")                                                     \
            for (int q = 0; q < 4; ++q) {                                         \
                a0 = __builtin_amdgcn_fdot2(u.h[q], w[0][4 * i + q], a0, false);  \
                a1 = __builtin_amdgcn_fdot2(u.h[q], w[1][4 * i + q], a1, false);  \
                a2 = __builtin_amdgcn_fdot2(u.h[q], w[2][4 * i + q], a2, false);  \
                a3 = __builtin_amdgcn_fdot2(u.h[q], w[3][4 * i + q], a3, false);  \
            }                                                                     \
        }                                                                         \
        a0 += dpp_xor1(a0); a0 += dpp_xor2(a0);                                   \
        a1 += dpp_xor1(a1); a1 += dpp_xor2(a1);                                   \
        a2 += dpp_xor1(a2); a2 += dpp_xor2(a2);                                   \
        a3 += dpp_xor1(a3); a3 += dpp_xor2(a3);                                   \
        const float p = (k & 1) ? ((k & 2) ? a3 : a1) : ((k & 2) ? a2 : a0);      \
        const float hn = fast_tanh(xc + p);                                       \
        encp[(S) * HH] = hn;                                                      \
        *(_Float16*)(hwr + hoff) = (_Float16)hn;                                  \
        asm volatile("s_waitcnt lgkmcnt(0)\n\ts_barrier" ::: "memory");           \
        { const char* tmp_ = hrd; hrd = hwr; hwr = (char*)tmp_; }                 \
    }

    // groups tb=0..504: steps t=tb..tb+3, prefetch t=tb+4..tb+7 (<=511: in bounds)
    for (int tb = 0; tb < TT - 4; tb += 4) {
        SCAN_STEP(0, 1)
        SCAN_STEP(1, 1)
        SCAN_STEP(2, 1)
        SCAN_STEP(3, 1)
        xpf  += 4 * HH;
        encp += 4 * HH;
    }
    // tail t=508..511: already prefetched, no further loads
    SCAN_STEP(0, 0)
    SCAN_STEP(1, 0)
    SCAN_STEP(2, 0)
    SCAN_STEP(3, 0)
#undef SCAN_STEP
}

// ---------------- K3: heads + tridiagonal fill ----------------
__global__ __launch_bounds__(256) void head_kernel(
    const float* __restrict__ enc,
    const float* __restrict__ W_mean, const float* __restrict__ b_mean,
    const float* __restrict__ W_bd, const float* __restrict__ b_bd,
    float* __restrict__ mean_out, float* __restrict__ prec)
{
    const int b = blockIdx.x >> 6;
    const int t0 = (blockIdx.x & 63) * 8;
    __shared__ __align__(16) float erow[9][HH];  // rows t0-1 .. t0+7
    __shared__ float vals[8][32];

    const int tid = threadIdx.x;
    {
        // row t0-1 (for t0==0,b==0 this reads the tail of xp — harmless, discarded)
        const float4* src = (const float4*)(enc + ((size_t)b * TT + t0) * HH - HH);
        float4* dst = (float4*)erow;
        for (int i = tid; i < 9 * (HH / 4); i += 256) dst[i] = src[i];
    }

    const int g = tid >> 3, m = tid & 7;
    const float* wrow;
    float bias;
    if (g < 8)       { wrow = W_mean + (size_t)g * HH;      bias = b_mean[g]; }
    else if (g < 24) { wrow = W_bd + (size_t)(g - 8) * HH;  bias = b_bd[g - 8]; }
    else             { wrow = W_bd + (size_t)(g - 16) * HH; bias = b_bd[g - 16]; }

    float4 wv[8];
#pragma unroll
    for (int i = 0; i < 8; ++i) wv[i] = ((const float4*)wrow)[m * 8 + i];

    __syncthreads();

    for (int r = 0; r < 8; ++r) {
        const float* src = (g >= 24) ? erow[r] : erow[r + 1];
        float acc = 0.f;
#pragma unroll
        for (int i = 0; i < 8; ++i) {
            const float4 hv = ((const float4*)src)[m * 8 + i];
            acc += wv[i].x * hv.x + wv[i].y * hv.y + wv[i].z * hv.z + wv[i].w * hv.w;
        }
        acc += dpp_xor1(acc);
        acc += dpp_xor2(acc);
        acc += __shfl_xor(acc, 4);
        if (m == 0) vals[r][g] = acc + bias;
    }
    __syncthreads();

    // write phase: 256 threads = 8 r-slots x 32 lanes
    const int r = tid >> 5, s = tid & 31;
    const int t = t0 + r;
    if (s < DD) {
        mean_out[((size_t)b * TT + t) * DD + s] = vals[r][s];
    } else if (s < 2 * DD) {
        const int d = s - DD;
        const float diag = vals[r][8 + d];
        const float off  = vals[r][16 + d];
        const float offp = (t > 0) ? vals[r][24 + d] : 0.f;
        const size_t rowbase = (((size_t)b * DD + d) * TT + t) * TT;
        prec[rowbase + t] = diag * diag + offp * offp + EPSF;
        if (t < TT - 1) {
            const float sv = diag * off;
            prec[rowbase + t + 1] = sv;                                 // (t, t+1)
            prec[(((size_t)b * DD + d) * TT + (t + 1)) * TT + t] = sv;  // (t+1, t)
        }
    }
}

extern "C" void kernel_launch(void* const* d_in, const int* in_sizes, int n_in,
                              void* d_out, int out_size, void* d_ws, size_t ws_size,
                              hipStream_t stream) {
    const float* y      = (const float*)d_in[0];
    const float* W_ih   = (const float*)d_in[1];
    const float* W_hh   = (const float*)d_in[2];
    const float* b_ih   = (const float*)d_in[3];
    const float* b_hh   = (const float*)d_in[4];
    const float* W_mean = (const float*)d_in[5];
    const float* b_mean = (const float*)d_in[6];
    const float* W_bd   = (const float*)d_in[7];
    const float* b_bd   = (const float*)d_in[8];

    float* out  = (float*)d_out;
    float* mean = out;                              // B*T*D floats
    float* prec = out + (size_t)BB * TT * DD;       // B*D*T*T floats

    float* xp  = (float*)d_ws;                      // B*T*H floats = 8 MB
    float* enc = xp + (size_t)BB * TT * HH;         // B*T*H floats = 8 MB

    xproj_kernel<<<512, 512, 0, stream>>>(y, W_ih, b_ih, b_hh, xp);
    scan_fill_kernel<<<1008, 256, 0, stream>>>(xp, W_hh, enc, prec);
    head_kernel<<<1024, 256, 0, stream>>>(enc, W_mean, b_mean, W_bd, b_bd, mean, prec);
}